// Round 2
// baseline (387.649 us; speedup 1.0000x reference)
//
#include <hip/hip_runtime.h>
#include <hip/hip_bf16.h>

// Problem constants
#define N_ROWS 8192
#define D_DIM  1024
#define HALF_N 4096
constexpr float INV_T = 1.0f / 0.07f;   // 14.2857143 — also the fixed softmax max M

typedef __attribute__((ext_vector_type(8))) short short8;  // 8 bf16 (4 VGPRs)
typedef __attribute__((ext_vector_type(4))) float f32x4;

__device__ __forceinline__ unsigned short f2bf(float x) {
    __hip_bfloat16 h = __float2bfloat16(x);
    return *reinterpret_cast<unsigned short*>(&h);
}

// async global->LDS, 16B/lane. LDS dest is wave-uniform base + lane*16.
__device__ __forceinline__ void async_ld16(const void* g, void* lds) {
    __builtin_amdgcn_global_load_lds(
        (const __attribute__((address_space(1))) void*)g,
        (__attribute__((address_space(3))) void*)lds,
        16, 0, 0);
}

// ---------------------------------------------------------------------------
// Kernel 1: row norms + bf16 normalized copy + row_sum zeroing.
// One wave per row.
__global__ __launch_bounds__(256) void norm_kernel(const float* __restrict__ feat,
                                                   unsigned short* __restrict__ fn,
                                                   float* __restrict__ row_sum) {
    const int w = threadIdx.x >> 6, lane = threadIdx.x & 63;
    const int row = blockIdx.x * 4 + w;
    const float4* src = (const float4*)(feat + (size_t)row * D_DIM);
    float4 v[4];
    float ss = 0.f;
#pragma unroll
    for (int t = 0; t < 4; ++t) {
        v[t] = src[lane + 64 * t];
        ss += v[t].x * v[t].x + v[t].y * v[t].y + v[t].z * v[t].z + v[t].w * v[t].w;
    }
#pragma unroll
    for (int off = 32; off; off >>= 1) ss += __shfl_xor(ss, off);
    float nrm = fmaxf(sqrtf(ss), 1e-8f);
    if (lane == 0) row_sum[row] = 0.f;
    const float inv = 1.0f / nrm;
    ushort4* dst = (ushort4*)(fn + (size_t)row * D_DIM);
#pragma unroll
    for (int t = 0; t < 4; ++t) {
        ushort4 o;
        o.x = f2bf(v[t].x * inv);
        o.y = f2bf(v[t].y * inv);
        o.z = f2bf(v[t].z * inv);
        o.w = f2bf(v[t].w * inv);
        dst[lane + 64 * t] = o;
    }
}

// ---------------------------------------------------------------------------
// Kernel 2: flash-style sim GEMM (NT, A=B=fn) + fixed-max exp accumulation
// + target-similarity extraction (sim[i, (i+4096)&8191]).
// Block: 256 thr (4 waves). Row tile 128 (blockIdx.y), col group 512 = 4 x 128
// col tiles (blockIdx.x). BK=64, global_load_lds x16B with XOR-swizzled
// source units (unit' = unit ^ (row&7)) so ds_read_b128 is 2-way (free) on
// the 32 banks; 16x16x32 bf16 MFMA, 4x4 subtiles per wave.
__global__ __launch_bounds__(256) void simgemm_kernel(const unsigned short* __restrict__ fn,
                                                      float* __restrict__ row_sum,
                                                      float* __restrict__ s_target) {
    __shared__ __align__(16) unsigned short As[128 * 64];   // 16 KiB
    __shared__ __align__(16) unsigned short Bs[128 * 64];   // 16 KiB
    const int tid = threadIdx.x;
    const int w = tid >> 6, lane = tid & 63;
    const int q = lane >> 4, c16 = lane & 15;
    const int r0 = blockIdx.y * 128;
    const int cg0 = blockIdx.x * 512;
    const int wr = (w >> 1) * 64;  // wave's row base within tile
    const int wc = (w & 1) * 64;   // wave's col base within tile
    // staging geometry: chunk = 8 rows x 64 k (1 KiB); wave w stages chunks
    // w*4 .. w*4+3 of A and of B. Lane l -> row l>>3, physical unit l&7;
    // source unit is XOR-swizzled: (l&7) ^ (row&7).
    const int srow = lane >> 3;
    const int sunit = (lane & 7) ^ srow;   // row&7 == srow within a chunk

    float rs[4][4];                      // per-(row-subtile, reg) partial exp-sums
#pragma unroll
    for (int i = 0; i < 4; ++i)
#pragma unroll
        for (int r = 0; r < 4; ++r) rs[i][r] = 0.f;

    for (int ct = 0; ct < 4; ++ct) {
        const int c0 = cg0 + ct * 128;
        f32x4 acc[4][4];
#pragma unroll
        for (int i = 0; i < 4; ++i)
#pragma unroll
            for (int j = 0; j < 4; ++j) acc[i][j] = (f32x4){0.f, 0.f, 0.f, 0.f};

        for (int kt = 0; kt < 16; ++kt) {
            const int k0 = kt * 64;
            __syncthreads();  // previous k-step's reads done before overwrite
#pragma unroll
            for (int t = 0; t < 4; ++t) {
                const int ch = w * 4 + t;
                const size_t arow = (size_t)(r0 + ch * 8 + srow);
                async_ld16(fn + arow * D_DIM + k0 + sunit * 8, (void*)&As[ch * 512]);
                const size_t brow = (size_t)(c0 + ch * 8 + srow);
                async_ld16(fn + brow * D_DIM + k0 + sunit * 8, (void*)&Bs[ch * 512]);
            }
            __syncthreads();  // drains vmcnt(0): staging visible

#pragma unroll
            for (int h = 0; h < 2; ++h) {
                short8 af[4], bf[4];
#pragma unroll
                for (int i = 0; i < 4; ++i) {
                    const int ra = wr + i * 16 + c16;
                    const int u = (h * 4 + q) ^ (ra & 7);
                    af[i] = *(const short8*)&As[ra * 64 + u * 8];
                }
#pragma unroll
                for (int j = 0; j < 4; ++j) {
                    const int rb = wc + j * 16 + c16;
                    const int u = (h * 4 + q) ^ (rb & 7);
                    bf[j] = *(const short8*)&Bs[rb * 64 + u * 8];
                }
#pragma unroll
                for (int i = 0; i < 4; ++i)
#pragma unroll
                    for (int j = 0; j < 4; ++j)
                        acc[i][j] = __builtin_amdgcn_mfma_f32_16x16x32_bf16(af[i], bf[j], acc[i][j], 0, 0, 0);
            }
        }

        // epilogue: exp(sim - M), diag masked, target extracted, row-accumulate
#pragma unroll
        for (int i = 0; i < 4; ++i) {
            const int growb = r0 + wr + i * 16 + q * 4;
#pragma unroll
            for (int r = 0; r < 4; ++r) {
                const int grow = growb + r;
                const int pcol = (grow + HALF_N) & (N_ROWS - 1);
                float s = 0.f;
#pragma unroll
                for (int j = 0; j < 4; ++j) {
                    const int gcol = c0 + wc + j * 16 + c16;
                    float sim = acc[i][j][r] * INV_T;
                    float e = __expf(sim - INV_T);
                    if (grow == gcol) e = 0.f;           // diagonal mask
                    if (gcol == pcol) s_target[grow] = sim;  // label similarity
                    s += e;
                }
                rs[i][r] += s;
            }
        }
    }

    // reduce across the 16 col-lanes of each quad, one atomic per row
#pragma unroll
    for (int i = 0; i < 4; ++i)
#pragma unroll
        for (int r = 0; r < 4; ++r) {
            float s = rs[i][r];
            s += __shfl_xor(s, 1);
            s += __shfl_xor(s, 2);
            s += __shfl_xor(s, 4);
            s += __shfl_xor(s, 8);
            if (c16 == 0) atomicAdd(&row_sum[r0 + wr + i * 16 + q * 4 + r], s);
        }
}

// ---------------------------------------------------------------------------
// Kernel 3: loss = mean_i [ M + log(row_sum_i) - s_target_i ]
__global__ __launch_bounds__(256) void loss_kernel(const float* __restrict__ row_sum,
                                                   const float* __restrict__ s_target,
                                                   float* __restrict__ out) {
    float local = 0.f;
    for (int i = threadIdx.x; i < N_ROWS; i += 256)
        local += (INV_T + __logf(row_sum[i])) - s_target[i];
#pragma unroll
    for (int off = 32; off; off >>= 1) local += __shfl_xor(local, off);
    __shared__ float part[4];
    if ((threadIdx.x & 63) == 0) part[threadIdx.x >> 6] = local;
    __syncthreads();
    if (threadIdx.x == 0)
        out[0] = (part[0] + part[1] + part[2] + part[3]) * (1.0f / N_ROWS);
}

// ---------------------------------------------------------------------------
extern "C" void kernel_launch(void* const* d_in, const int* in_sizes, int n_in,
                              void* d_out, int out_size, void* d_ws, size_t ws_size,
                              hipStream_t stream) {
    const float* feat = (const float*)d_in[0];
    float* out = (float*)d_out;
    char* ws = (char*)d_ws;

    unsigned short* fn = (unsigned short*)ws;                 // 8192*1024 bf16 = 16 MiB
    size_t off = (size_t)N_ROWS * D_DIM * sizeof(unsigned short);
    float* row_sum = (float*)(ws + off);  off += N_ROWS * sizeof(float);
    float* s_target = (float*)(ws + off);

    norm_kernel<<<N_ROWS / 4, 256, 0, stream>>>(feat, fn, row_sum);
    simgemm_kernel<<<dim3(16, 64), 256, 0, stream>>>(fn, row_sum, s_target);
    loss_kernel<<<1, 256, 0, stream>>>(row_sum, s_target, out);
}

// Round 3
// 369.246 us; speedup vs baseline: 1.0498x; 1.0498x over previous
//
#include <hip/hip_runtime.h>
#include <hip/hip_bf16.h>

// Problem constants
#define N_ROWS 8192
#define D_DIM  1024
#define HALF_N 4096
constexpr float INV_T = 1.0f / 0.07f;   // 14.2857143 — also the fixed softmax max M

typedef __attribute__((ext_vector_type(8))) short short8;  // 8 bf16 (4 VGPRs)
typedef __attribute__((ext_vector_type(4))) float f32x4;

__device__ __forceinline__ unsigned short f2bf(float x) {
    __hip_bfloat16 h = __float2bfloat16(x);
    return *reinterpret_cast<unsigned short*>(&h);
}

// async global->LDS, 16B/lane. LDS dest is wave-uniform base + lane*16.
__device__ __forceinline__ void async_ld16(const void* g, void* lds) {
    __builtin_amdgcn_global_load_lds(
        (const __attribute__((address_space(1))) void*)g,
        (__attribute__((address_space(3))) void*)lds,
        16, 0, 0);
}

// ---------------------------------------------------------------------------
// Kernel 1: row norms + bf16 normalized copy + row_sum zeroing.
// One wave per row.
__global__ __launch_bounds__(256) void norm_kernel(const float* __restrict__ feat,
                                                   unsigned short* __restrict__ fn,
                                                   float* __restrict__ row_sum) {
    const int w = threadIdx.x >> 6, lane = threadIdx.x & 63;
    const int row = blockIdx.x * 4 + w;
    const float4* src = (const float4*)(feat + (size_t)row * D_DIM);
    float4 v[4];
    float ss = 0.f;
#pragma unroll
    for (int t = 0; t < 4; ++t) {
        v[t] = src[lane + 64 * t];
        ss += v[t].x * v[t].x + v[t].y * v[t].y + v[t].z * v[t].z + v[t].w * v[t].w;
    }
#pragma unroll
    for (int off = 32; off; off >>= 1) ss += __shfl_xor(ss, off);
    float nrm = fmaxf(sqrtf(ss), 1e-8f);
    if (lane == 0) row_sum[row] = 0.f;
    const float inv = 1.0f / nrm;
    ushort4* dst = (ushort4*)(fn + (size_t)row * D_DIM);
#pragma unroll
    for (int t = 0; t < 4; ++t) {
        ushort4 o;
        o.x = f2bf(v[t].x * inv);
        o.y = f2bf(v[t].y * inv);
        o.z = f2bf(v[t].z * inv);
        o.w = f2bf(v[t].w * inv);
        dst[lane + 64 * t] = o;
    }
}

// ---------------------------------------------------------------------------
// Kernel 2: flash-style sim GEMM (NT, A=B=fn) + fixed-max exp accumulation
// + target-similarity extraction (sim[i, (i+4096)&8191]).
// Round-1 structure (BK=32, 16 KiB LDS, register-lean: 112 VGPR, 2 waves/SIMD)
// + XOR-swizzled LDS units: physical 16B-unit p = logical q ^ ((row>>1)&3).
// Bank-start per lane = (row*16 + 4p) mod 32 -> each 4-bank group gets exactly
// 2 of the 16 lanes of a ds_read_b128 -> 2-way aliasing = free (m136).
// Swizzle lives in the *global source address* of global_load_lds (dest is
// fixed base+lane*16), so it costs no k-loop VALU: LDS read addresses are
// kt-invariant and hoisted.
__global__ __launch_bounds__(256) void simgemm_kernel(const unsigned short* __restrict__ fn,
                                                      float* __restrict__ row_sum,
                                                      float* __restrict__ s_target) {
    __shared__ __align__(16) unsigned short As[128 * 32];   // 8 KiB
    __shared__ __align__(16) unsigned short Bs[128 * 32];   // 8 KiB
    const int tid = threadIdx.x;
    const int w = tid >> 6, lane = tid & 63;
    const int q = lane >> 4, c16 = lane & 15;
    const int r0 = blockIdx.y * 128;
    const int cg0 = blockIdx.x * 512;
    const int wr = (w >> 1) * 64;  // wave's row base within tile
    const int wc = (w & 1) * 64;   // wave's col base within tile
    // staging geometry: chunk = 16 rows x 32 k (1 KiB); wave w stages chunks
    // 2w, 2w+1 of A and B. Lane l -> chunk row l>>2, physical unit l&3;
    // fetch logical unit (l&3) ^ f(row), f(row) = (row>>1)&3.
    const int srow = lane >> 2;
    const int skoff = ((lane & 3) ^ ((srow >> 1) & 3)) * 8;  // element offset

    float rs[4][4];                      // per-(row-subtile, reg) partial exp-sums
#pragma unroll
    for (int i = 0; i < 4; ++i)
#pragma unroll
        for (int r = 0; r < 4; ++r) rs[i][r] = 0.f;

    for (int ct = 0; ct < 4; ++ct) {
        const int c0 = cg0 + ct * 128;
        f32x4 acc[4][4];
#pragma unroll
        for (int i = 0; i < 4; ++i)
#pragma unroll
            for (int j = 0; j < 4; ++j) acc[i][j] = (f32x4){0.f, 0.f, 0.f, 0.f};

        for (int kt = 0; kt < 32; ++kt) {
            const int k0 = kt * 32;
            __syncthreads();  // previous k-step's reads done before overwrite
#pragma unroll
            for (int cc = 0; cc < 2; ++cc) {
                const int ch = w * 2 + cc;
                const size_t arow = (size_t)(r0 + ch * 16 + srow);
                async_ld16(fn + arow * D_DIM + k0 + skoff, (void*)&As[ch * 512]);
                const size_t brow = (size_t)(c0 + ch * 16 + srow);
                async_ld16(fn + brow * D_DIM + k0 + skoff, (void*)&Bs[ch * 512]);
            }
            __syncthreads();  // drains vmcnt(0): staging visible

            short8 af[4], bf[4];
#pragma unroll
            for (int i = 0; i < 4; ++i) {
                const int ra = wr + i * 16 + c16;
                af[i] = *(const short8*)&As[ra * 32 + ((q ^ ((ra >> 1) & 3))) * 8];
            }
#pragma unroll
            for (int j = 0; j < 4; ++j) {
                const int rb = wc + j * 16 + c16;
                bf[j] = *(const short8*)&Bs[rb * 32 + ((q ^ ((rb >> 1) & 3))) * 8];
            }
#pragma unroll
            for (int i = 0; i < 4; ++i)
#pragma unroll
                for (int j = 0; j < 4; ++j)
                    acc[i][j] = __builtin_amdgcn_mfma_f32_16x16x32_bf16(af[i], bf[j], acc[i][j], 0, 0, 0);
        }

        // epilogue: exp(sim - M), diag masked, target extracted, row-accumulate
#pragma unroll
        for (int i = 0; i < 4; ++i) {
            const int growb = r0 + wr + i * 16 + q * 4;
#pragma unroll
            for (int r = 0; r < 4; ++r) {
                const int grow = growb + r;
                const int pcol = (grow + HALF_N) & (N_ROWS - 1);
                float s = 0.f;
#pragma unroll
                for (int j = 0; j < 4; ++j) {
                    const int gcol = c0 + wc + j * 16 + c16;
                    float sim = acc[i][j][r] * INV_T;
                    float e = __expf(sim - INV_T);
                    if (grow == gcol) e = 0.f;               // diagonal mask
                    if (gcol == pcol) s_target[grow] = sim;  // label similarity
                    s += e;
                }
                rs[i][r] += s;
            }
        }
    }

    // reduce across the 16 col-lanes of each quad, one atomic per row
#pragma unroll
    for (int i = 0; i < 4; ++i)
#pragma unroll
        for (int r = 0; r < 4; ++r) {
            float s = rs[i][r];
            s += __shfl_xor(s, 1);
            s += __shfl_xor(s, 2);
            s += __shfl_xor(s, 4);
            s += __shfl_xor(s, 8);
            if (c16 == 0) atomicAdd(&row_sum[r0 + wr + i * 16 + q * 4 + r], s);
        }
}

// ---------------------------------------------------------------------------
// Kernel 3: loss = mean_i [ M + log(row_sum_i) - s_target_i ]
__global__ __launch_bounds__(256) void loss_kernel(const float* __restrict__ row_sum,
                                                   const float* __restrict__ s_target,
                                                   float* __restrict__ out) {
    float local = 0.f;
    for (int i = threadIdx.x; i < N_ROWS; i += 256)
        local += (INV_T + __logf(row_sum[i])) - s_target[i];
#pragma unroll
    for (int off = 32; off; off >>= 1) local += __shfl_xor(local, off);
    __shared__ float part[4];
    if ((threadIdx.x & 63) == 0) part[threadIdx.x >> 6] = local;
    __syncthreads();
    if (threadIdx.x == 0)
        out[0] = (part[0] + part[1] + part[2] + part[3]) * (1.0f / N_ROWS);
}

// ---------------------------------------------------------------------------
extern "C" void kernel_launch(void* const* d_in, const int* in_sizes, int n_in,
                              void* d_out, int out_size, void* d_ws, size_t ws_size,
                              hipStream_t stream) {
    const float* feat = (const float*)d_in[0];
    float* out = (float*)d_out;
    char* ws = (char*)d_ws;

    unsigned short* fn = (unsigned short*)ws;                 // 8192*1024 bf16 = 16 MiB
    size_t off = (size_t)N_ROWS * D_DIM * sizeof(unsigned short);
    float* row_sum = (float*)(ws + off);  off += N_ROWS * sizeof(float);
    float* s_target = (float*)(ws + off);

    norm_kernel<<<N_ROWS / 4, 256, 0, stream>>>(feat, fn, row_sum);
    simgemm_kernel<<<dim3(16, 64), 256, 0, stream>>>(fn, row_sum, s_target);
    loss_kernel<<<1, 256, 0, stream>>>(row_sum, s_target, out);
}